// Round 5
// baseline (1368.432 us; speedup 1.0000x reference)
//
#include <hip/hip_runtime.h>
#include <hip/hip_bf16.h>

#define N_ATOMS 25000
#define N_PAIRS 500000
#define DEPTH 4
#define TILE 192
#define PTHREADS 768

typedef _Float16 f16x8 __attribute__((ext_vector_type(8)));
typedef float f32x16 __attribute__((ext_vector_type(16)));
typedef unsigned short u16;

__device__ __forceinline__ float tanh_fast(float x) {
    // tanh(x) = 1 - 2/(exp(2x)+1); saturates correctly at +/-inf
    float e = __expf(2.0f * x);
    return 1.0f - 2.0f * __builtin_amdgcn_rcpf(e + 1.0f);
}

__device__ __forceinline__ void split_h(float x, u16& hi, u16& lo) {
    _Float16 h = (_Float16)x;                 // RNE
    _Float16 l = (_Float16)(x - (float)h);    // residual, RNE
    hi = *(u16*)&h;
    lo = *(u16*)&l;
}

// LDS bank-swizzle on 16B-unit index (involution within 128B block).
// Verified: SQ_LDS_BANK_CONFLICT 2.02e7 -> 0 (rounds 1-3).
__device__ __forceinline__ int swz8(int u) { return u ^ ((u >> 5) & 7); }

// ---------------- prep: split weights to hi/lo fp16, fragment-major images
// img1 per depth: [hl][ntw][ks(8)][l(64)][j(8)]  (unused since R5, kept for layout stability)
// img2 per depth: [hl][ntw][t(4)][ks(4)][l][j]         = 32768 u16  (cols permuted: n=4*ch+t)
// imgab per depth: [stage][hl][ntw][ks(4)][l][j]       = 16384 u16
__global__ __launch_bounds__(256)
void prep_kernel(const float* __restrict__ piW1, const float* __restrict__ piW2,
                 const float* __restrict__ iiW1, const float* __restrict__ iiW2,
                 u16* __restrict__ img1, u16* __restrict__ img2, u16* __restrict__ imgab) {
    int gid = blockIdx.x * 256 + threadIdx.x;     // 512 blocks * 256 = 131072 = 4*32768
    int d = gid >> 15, e = gid & 32767;
    u16 hi, lo;
    if (e < 8192) {                 // W1 [k=128][n=64]
        int k = e >> 6, n = e & 63;
        split_h(piW1[d * 8192 + e], hi, lo);
        int ntw = n >> 5, colb = n & 31;
        int ks = k >> 4, lh = (k >> 3) & 1, j = k & 7;
        int off = ((ntw * 8 + ks) * 64 + lh * 32 + colb) * 8 + j;
        img1[d * 16384 + 0 * 8192 + off] = hi;
        img1[d * 16384 + 1 * 8192 + off] = lo;
    } else if (e < 24576) {         // W2 [k=64][n=256], permuted n = 4*ch + t
        int s = e - 8192;
        int k = s >> 8, n = s & 255;
        split_h(piW2[d * 16384 + s], hi, lo);
        int ch = n >> 2, t = n & 3;
        int ntw = ch >> 5, colb = ch & 31;
        int ks = k >> 4, lh = (k >> 3) & 1, j = k & 7;
        int off = (((ntw * 4 + t) * 4 + ks) * 64 + lh * 32 + colb) * 8 + j;
        img2[d * 32768 + 0 * 16384 + off] = hi;
        img2[d * 32768 + 1 * 16384 + off] = lo;
    } else {                        // Wa (stage0) / Wb (stage1), [k=64][n=64]
        int stage = (e < 28672) ? 0 : 1;
        int s = e - (stage ? 28672 : 24576);
        int k = s >> 6, n = s & 63;
        float x = stage ? iiW2[d * 4096 + s] : iiW1[d * 4096 + s];
        split_h(x, hi, lo);
        int ntw = n >> 5, colb = n & 31;
        int ks = k >> 4, lh = (k >> 3) & 1, j = k & 7;
        int off = ((ntw * 4 + ks) * 64 + lh * 32 + colb) * 8 + j;
        imgab[d * 16384 + (stage * 2 + 0) * 4096 + off] = hi;
        imgab[d * 16384 + (stage * 2 + 1) * 4096 + off] = lo;
    }
}

__global__ __launch_bounds__(256)
void prep_b2(const float* __restrict__ piB2, float* __restrict__ b2p) {
    int d = blockIdx.x, n = threadIdx.x;
    int ch = n >> 2, t = n & 3;
    int np = (ch >> 5) * 128 + t * 32 + (ch & 31);
    b2p[d * 256 + np] = piB2[d * 256 + n];
}

// ---------------- atom-level MLP (fp32 VALU); also emits U = h@W1_top, V = h@W1_bot
template <int K, bool IS_D0>
__global__ __launch_bounds__(256)
void atom_mlp(const float* __restrict__ p_in,
              const float* __restrict__ W1, const float* __restrict__ b1,
              const float* __restrict__ W2, const float* __restrict__ b2,
              const float* __restrict__ res0_w,
              const float* __restrict__ piW1d,
              float* __restrict__ Uo, float* __restrict__ Vo,
              float* __restrict__ acc_out) {
    __shared__ float sP[4][64];
    __shared__ float sH[4][64];
    __shared__ float sH2[4][64];
    int tid = threadIdx.x;
    int al = tid >> 6, c = tid & 63;
    int a = blockIdx.x * 4 + al;
    if (c < K) sP[al][c] = p_in[a * K + c];
    __syncthreads();
    float s = b1[c];
#pragma unroll
    for (int k = 0; k < K; ++k) s += sP[al][k] * W1[k * 64 + c];
    float t1 = tanh_fast(s);
    float r;
    if (IS_D0) {
        r = 0.f;
#pragma unroll
        for (int k = 0; k < 16; ++k) r += sP[al][k] * res0_w[k * 64 + c];
    } else {
        r = sP[al][c];
    }
    acc_out[a * 64 + c] = r;
    sH[al][c] = t1;
    __syncthreads();
    float s2 = b2[c];
#pragma unroll
    for (int k = 0; k < 64; ++k) s2 += sH[al][k] * W2[k * 64 + c];
    float hv = tanh_fast(s2);
    sH2[al][c] = hv;
    __syncthreads();
    float su = 0.f, sv = 0.f;
#pragma unroll
    for (int k = 0; k < 64; ++k) {
        float x = sH2[al][k];
        su += x * piW1d[k * 64 + c];
        sv += x * piW1d[(64 + k) * 64 + c];
    }
    Uo[a * 64 + c] = su;
    Vo[a * 64 + c] = sv;
}

// ---------------- output head (fp32), standalone (after last depth)
__global__ __launch_bounds__(256)
void out_kernel(const float* __restrict__ p,
                const float* __restrict__ W1, const float* __restrict__ b1,
                const float* __restrict__ W2, const float* __restrict__ b2,
                const float* __restrict__ wo,
                float* __restrict__ out, int store) {
    __shared__ float sP[4][64];
    __shared__ float sH[4][64];
    int tid = threadIdx.x;
    int al = tid >> 6, c = tid & 63;
    int a = blockIdx.x * 4 + al;
    sP[al][c] = p[a * 64 + c];
    __syncthreads();
    float s = b1[c];
#pragma unroll
    for (int k = 0; k < 64; ++k) s += sP[al][k] * W1[k * 64 + c];
    sH[al][c] = tanh_fast(s);
    __syncthreads();
    float s2 = b2[c];
#pragma unroll
    for (int k = 0; k < 64; ++k) s2 += sH[al][k] * W2[k * 64 + c];
    float v = tanh_fast(s2) * wo[c];
#pragma unroll
    for (int off = 32; off > 0; off >>= 1) v += __shfl_down(v, off, 64);
    if (c == 0) {
        if (store) out[a] = v;
        else out[a] += v;
    }
}

// ---------------- fused: out head of depth d + atom MLP of depth d+1 (+U/V emit)
__global__ __launch_bounds__(256)
void fused_out_atom(const float* __restrict__ p,
                    const float* __restrict__ oW1, const float* __restrict__ ob1,
                    const float* __restrict__ oW2, const float* __restrict__ ob2,
                    const float* __restrict__ wo,
                    const float* __restrict__ aW1, const float* __restrict__ ab1,
                    const float* __restrict__ aW2, const float* __restrict__ ab2,
                    float* __restrict__ out, int store,
                    const float* __restrict__ piW1d,
                    float* __restrict__ Uo, float* __restrict__ Vo,
                    float* __restrict__ acc_out) {
    __shared__ float sP[4][64];
    __shared__ float sHo[4][64];
    __shared__ float sHa[4][64];
    int tid = threadIdx.x;
    int al = tid >> 6, c = tid & 63;
    int a = blockIdx.x * 4 + al;
    float pv = p[a * 64 + c];
    sP[al][c] = pv;
    acc_out[a * 64 + c] = pv;            // residual base for next depth
    __syncthreads();
    float so = ob1[c], sa = ab1[c];
#pragma unroll
    for (int k = 0; k < 64; ++k) {
        float x = sP[al][k];
        so += x * oW1[k * 64 + c];
        sa += x * aW1[k * 64 + c];
    }
    sHo[al][c] = tanh_fast(so);
    sHa[al][c] = tanh_fast(sa);
    __syncthreads();
    float s2o = ob2[c], s2a = ab2[c];
#pragma unroll
    for (int k = 0; k < 64; ++k) {
        s2o += sHo[al][k] * oW2[k * 64 + c];
        s2a += sHa[al][k] * aW2[k * 64 + c];
    }
    float v = tanh_fast(s2o) * wo[c];
#pragma unroll
    for (int off = 32; off > 0; off >>= 1) v += __shfl_down(v, off, 64);
    if (c == 0) {
        if (store) out[a] = v;
        else out[a] += v;
    }
    float hv = tanh_fast(s2a);
    sP[al][c] = hv;                      // sP dead after loop1; reuse for h
    __syncthreads();
    float su = 0.f, sv = 0.f;
#pragma unroll
    for (int k = 0; k < 64; ++k) {
        float x = sP[al][k];
        su += x * piW1d[k * 64 + c];
        sv += x * piW1d[(64 + k) * 64 + c];
    }
    Uo[a * 64 + c] = su;
    Vo[a * 64 + c] = sv;
}

// ---------------- pair pipeline v2: G1 eliminated (U[i]+V[j] gather), 12 waves
#define MFMA __builtin_amdgcn_mfma_f32_32x32x16_f16

__global__ __launch_bounds__(PTHREADS, 3)
void pair_kernel(const float* __restrict__ Uin,
                 const float* __restrict__ Vin,
                 const int* __restrict__ ind2,
                 const float* __restrict__ basis,
                 const u16* __restrict__ img2,
                 const u16* __restrict__ imgab,
                 const float* __restrict__ piB1,
                 const float* __restrict__ b2p,
                 float* __restrict__ accp) {
    __shared__ __attribute__((aligned(16))) _Float16 sW2[32768];   // 64 KB  pi_w2 hi+lo frags
    __shared__ __attribute__((aligned(16))) u16 sAB[16384];        // 32 KB  ii_w1/ii_w2 hi+lo frags
    __shared__ __attribute__((aligned(16))) _Float16 bufA[12288];  // 24 KB  G1out / G3out frags (swz)
    __shared__ __attribute__((aligned(16))) _Float16 bufB[12288];  // 24 KB  inter frags (swz)
    __shared__ float sBas[TILE * 4];                               //  3 KB
    __shared__ int sIdx[TILE];                                     // 0.75 KB
    // total ~148 KB -> 1 block/CU, 12 waves = 3 waves/SIMD

    const int tid = threadIdx.x;
    for (int i = tid; i < 4096; i += PTHREADS) ((uint4*)sW2)[i] = ((const uint4*)img2)[i];
    for (int i = tid; i < 2048; i += PTHREADS) ((uint4*)sAB)[i] = ((const uint4*)imgab)[i];

    const int l = tid & 63;
    const int w = tid >> 6;
    const int mt = w >> 1, ntw = w & 1;      // mt 0..5, ntw 0..1
    const int col = l & 31, kg = l >> 5;
    const int ch = ntw * 32 + col;
    const int chks = ch >> 4, chlh = (ch >> 3) & 1, chj = ch & 7;

    // swizzle bases (proven identical to swz8 forms in R2/R3):
    //   read  addr = buf + mt*4096 + ks*1024 + rb[ks]
    //   write addr = buf + wb[r&3] + (r>>2)*128
    int rb[4], wb[4];
    {
        const int wxor = 2 * chks + chlh;
#pragma unroll
        for (int c = 0; c < 4; ++c) {
            rb[c] = (l ^ (kg + 2 * c)) << 4;
            wb[c] = (mt * 4 + chks) * 1024 + chlh * 512 + ((((c) + 4 * kg) ^ wxor) << 4) + chj * 2;
        }
    }
    const int mts = mt << 12;

    // P1 thread mapping: 4 threads per row, 16 consecutive ch each
    const int m = tid >> 2, ksel = tid & 3;  // m 0..191
    const int mtd = m >> 5, lrow = m & 31;
    const int u0 = (mtd * 4 + ksel) * 64 + lrow;
    const int wA0 = swz8(u0) * 16, wA1 = swz8(u0 + 32) * 16;

    float b1p[16];
#pragma unroll
    for (int z = 0; z < 16; ++z) b1p[z] = piB1[ksel * 16 + z];
    float b2v[4];
#pragma unroll
    for (int t = 0; t < 4; ++t) b2v[t] = b2p[ntw * 128 + t * 32 + col];

    const int nTiles = (N_PAIRS + TILE - 1) / TILE;

    float ur[16], vr[16];
    auto loadUV = [&](int tile) {
        int p = tile * TILE + m;
        bool ok = (tile < nTiles) && (p < N_PAIRS);
        int2 ij = ok ? ((const int2*)ind2)[p] : make_int2(0, 0);
        const float* up = Uin + ij.x * 64 + ksel * 16;
        const float* vp = Vin + ij.y * 64 + ksel * 16;
        float4 z4 = make_float4(0.f, 0.f, 0.f, 0.f);
#pragma unroll
        for (int q = 0; q < 4; ++q) {
            float4 a = ok ? *(const float4*)(up + q * 4) : z4;
            float4 b = ok ? *(const float4*)(vp + q * 4) : z4;
            ur[q * 4 + 0] = a.x; ur[q * 4 + 1] = a.y; ur[q * 4 + 2] = a.z; ur[q * 4 + 3] = a.w;
            vr[q * 4 + 0] = b.x; vr[q * 4 + 1] = b.y; vr[q * 4 + 2] = b.z; vr[q * 4 + 3] = b.w;
        }
    };
    loadUV(blockIdx.x);

    for (int tile = blockIdx.x; tile < nTiles; tile += gridDim.x) {
        const int base = tile * TILE;

        // ---- P1: stage basis/idx; G1out = tanh(U[i]+V[j]+b1) -> bufA frags
        if (tid < TILE) {
            int p = base + tid;
            float4 bv = (p < N_PAIRS) ? ((const float4*)basis)[p] : make_float4(0.f, 0.f, 0.f, 0.f);
            *(float4*)&sBas[tid * 4] = bv;
            sIdx[tid] = (p < N_PAIRS) ? ind2[2 * p] : 0;
        }
        {
            f16x8 lo8, hi8;
#pragma unroll
            for (int z = 0; z < 8; ++z)
                lo8[z] = (_Float16)tanh_fast(ur[z] + vr[z] + b1p[z]);
#pragma unroll
            for (int z = 0; z < 8; ++z)
                hi8[z] = (_Float16)tanh_fast(ur[8 + z] + vr[8 + z] + b1p[8 + z]);
            *(f16x8*)((char*)bufA + wA0) = lo8;
            *(f16x8*)((char*)bufA + wA1) = hi8;
        }
        __syncthreads();

        // ---- P2 (G2): [192x64]@[64x256]+b2, tanh, basis contraction -> bufB
        {
            f16x8 afr[4];
#pragma unroll
            for (int ks = 0; ks < 4; ++ks)
                afr[ks] = *(const f16x8*)((const char*)bufA + mts + ks * 1024 + rb[ks]);
            float s[16];
#pragma unroll
            for (int r = 0; r < 16; ++r) s[r] = 0.f;
#pragma unroll
            for (int pp = 0; pp < 2; ++pp) {
                f32x16 a0 = {}, a1 = {};
                const int t0 = 2 * pp, t1 = 2 * pp + 1;
#pragma unroll
                for (int ks = 0; ks < 4; ++ks) {
                    a0 = MFMA(afr[ks], *(const f16x8*)(sW2 + ((ntw * 4 + t0) * 4 + ks) * 512 + l * 8), a0, 0, 0, 0);
                    a0 = MFMA(afr[ks], *(const f16x8*)(sW2 + 16384 + ((ntw * 4 + t0) * 4 + ks) * 512 + l * 8), a0, 0, 0, 0);
                    a1 = MFMA(afr[ks], *(const f16x8*)(sW2 + ((ntw * 4 + t1) * 4 + ks) * 512 + l * 8), a1, 0, 0, 0);
                    a1 = MFMA(afr[ks], *(const f16x8*)(sW2 + 16384 + ((ntw * 4 + t1) * 4 + ks) * 512 + l * 8), a1, 0, 0, 0);
                }
#pragma unroll
                for (int r = 0; r < 16; ++r) {
                    int lr2 = (r & 3) + 8 * (r >> 2) + 4 * kg;
                    int row = mt * 32 + lr2;
                    float2 bb = *(const float2*)&sBas[row * 4 + 2 * pp];
                    s[r] += tanh_fast(a0[r] + b2v[t0]) * bb.x + tanh_fast(a1[r] + b2v[t1]) * bb.y;
                }
            }
#pragma unroll
            for (int r = 0; r < 16; ++r)
                *(u16*)((char*)bufB + wb[r & 3] + ((r >> 2) << 7)) =
                    __builtin_bit_cast(u16, (_Float16)s[r]);
        }
        __syncthreads();

        // ---- P3 (G3): inter @ ii_w1 (hi+lo from LDS), tanh -> bufA
        {
            f32x16 ah = {}, al2 = {};
#pragma unroll
            for (int ks = 0; ks < 4; ++ks) {
                f16x8 a = *(const f16x8*)((const char*)bufB + mts + ks * 1024 + rb[ks]);
                ah  = MFMA(a, *(const f16x8*)(sAB + 0 * 4096 + ntw * 2048 + ks * 512 + l * 8), ah, 0, 0, 0);
                al2 = MFMA(a, *(const f16x8*)(sAB + 1 * 4096 + ntw * 2048 + ks * 512 + l * 8), al2, 0, 0, 0);
            }
#pragma unroll
            for (int r = 0; r < 16; ++r)
                *(u16*)((char*)bufA + wb[r & 3] + ((r >> 2) << 7)) =
                    __builtin_bit_cast(u16, (_Float16)tanh_fast(ah[r] + al2[r]));
        }
        __syncthreads();

        // ---- P4 (G4): @ ii_w2, tanh, atomic scatter; prefetch next-tile U/V
        {
            f16x8 afr[4];
#pragma unroll
            for (int ks = 0; ks < 4; ++ks)
                afr[ks] = *(const f16x8*)((const char*)bufA + mts + ks * 1024 + rb[ks]);

            loadUV(tile + gridDim.x);    // regs only; consumed next P1

            f32x16 ah = {}, al2 = {};
#pragma unroll
            for (int ks = 0; ks < 4; ++ks) {
                ah  = MFMA(afr[ks], *(const f16x8*)(sAB + 2 * 4096 + ntw * 2048 + ks * 512 + l * 8), ah, 0, 0, 0);
                al2 = MFMA(afr[ks], *(const f16x8*)(sAB + 3 * 4096 + ntw * 2048 + ks * 512 + l * 8), al2, 0, 0, 0);
            }
#pragma unroll
            for (int r = 0; r < 16; ++r) {
                int lr2 = (r & 3) + 8 * (r >> 2) + 4 * kg;
                int p = base + mt * 32 + lr2;
                if (p < N_PAIRS)
                    atomicAdd(&accp[sIdx[mt * 32 + lr2] * 64 + ch], tanh_fast(ah[r] + al2[r]));
            }
        }
        __syncthreads();
    }
}

extern "C" void kernel_launch(void* const* d_in, const int* in_sizes, int n_in,
                              void* d_out, int out_size, void* d_ws, size_t ws_size,
                              hipStream_t stream) {
    const int* ind2 = (const int*)d_in[0];
    const float* prop = (const float*)d_in[1];
    const float* basis = (const float*)d_in[2];
    const float* pp0_w1 = (const float*)d_in[3];
    const float* pp0_b1 = (const float*)d_in[4];
    const float* pp_w1 = (const float*)d_in[5];
    const float* pp_b1 = (const float*)d_in[6];
    const float* pp_w2 = (const float*)d_in[7];
    const float* pp_b2 = (const float*)d_in[8];
    const float* pi_w1 = (const float*)d_in[9];
    const float* pi_b1 = (const float*)d_in[10];
    const float* pi_w2 = (const float*)d_in[11];
    const float* pi_b2 = (const float*)d_in[12];
    const float* ii_w1 = (const float*)d_in[13];
    const float* ii_w2 = (const float*)d_in[14];
    const float* res0_w = (const float*)d_in[15];
    const float* out_w1 = (const float*)d_in[16];
    const float* out_b1 = (const float*)d_in[17];
    const float* out_w2 = (const float*)d_in[18];
    const float* out_b2 = (const float*)d_in[19];
    const float* out_wo = (const float*)d_in[20];
    float* out = (float*)d_out;

    // workspace layout
    float* B0 = (float*)d_ws;                            // 25000*64 f32
    float* B1 = B0 + N_ATOMS * 64;                       // 25000*64 f32
    float* Ubuf = B1 + N_ATOMS * 64;                     // 25000*64 f32
    float* Vbuf = Ubuf + N_ATOMS * 64;                   // 25000*64 f32
    u16* img1 = (u16*)(Vbuf + N_ATOMS * 64);             // 4*16384 u16 (unused, layout kept)
    u16* img2 = img1 + 4 * 16384;                        // 4*32768 u16
    u16* imgab = img2 + 4 * 32768;                       // 4*16384 u16
    float* b2p = (float*)(imgab + 4 * 16384);            // 4*256 f32
    float* pbuf[2] = {B0, B1};

    prep_kernel<<<512, 256, 0, stream>>>(pi_w1, pi_w2, ii_w1, ii_w2, img1, img2, imgab);
    prep_b2<<<4, 256, 0, stream>>>(pi_b2, b2p);

    for (int d = 0; d < DEPTH; ++d) {
        float* acc = pbuf[d & 1];
        if (d == 0) {
            atom_mlp<16, true><<<N_ATOMS / 4, 256, 0, stream>>>(
                prop, pp0_w1, pp0_b1, pp_w2, pp_b2, res0_w,
                pi_w1, Ubuf, Vbuf, acc);
        } else {
            const float* pin = pbuf[(d - 1) & 1];
            fused_out_atom<<<N_ATOMS / 4, 256, 0, stream>>>(
                pin,
                out_w1 + (d - 1) * 4096, out_b1 + (d - 1) * 64,
                out_w2 + (d - 1) * 4096, out_b2 + (d - 1) * 64, out_wo + (d - 1) * 64,
                pp_w1 + (d - 1) * 4096, pp_b1 + (d - 1) * 64,
                pp_w2 + d * 4096, pp_b2 + d * 64,
                out, (d - 1) == 0 ? 1 : 0,
                pi_w1 + d * 8192, Ubuf, Vbuf, acc);
        }
        pair_kernel<<<256, PTHREADS, 0, stream>>>(
            Ubuf, Vbuf, ind2, basis,
            img2 + d * 32768, imgab + d * 16384,
            pi_b1 + d * 64, b2p + d * 256, acc);
    }
    out_kernel<<<N_ATOMS / 4, 256, 0, stream>>>(
        pbuf[(DEPTH - 1) & 1], out_w1 + (DEPTH - 1) * 4096, out_b1 + (DEPTH - 1) * 64,
        out_w2 + (DEPTH - 1) * 4096, out_b2 + (DEPTH - 1) * 64, out_wo + (DEPTH - 1) * 64,
        out, 0);
}